// Round 3
// baseline (1419.805 us; speedup 1.0000x reference)
//
#include <hip/hip_runtime.h>

// QBN_GRU_Base on MI355X.
// Ternary bottlenecks (dim 8) make the recurrence finite-state:
//   xq, q in {-1,0,1}^8 -> 6561 codes. Memoize
//     GI[code][64]   = xq@wih.T + bih            (packed [i*4+{r,z,n,pad}])
//     GHM[code][64]  = {m@whh.T + bhh, m}        (packed [i*4+{r,z,n,m}], row 6561 = h0 state)
//     Y[code][16]    = tanh(m@act_w.T + act_b)
// R3: one chain per WAVE (2048 waves). All cross-lane traffic via
// v_readlane (VALU/SALU) -> zero DS-pipe ops in the scan. qcode becomes
// wave-uniform -> saddr table loads, scalar xcode loads.
// Numerics: XLA/Eigen rational tanh, logistic = 0.5+0.5*tanh(0.5x), fma dots —
// all float expressions identical to the absmax==0.0 round-1 kernel.

#define T_DIM 512
#define B_DIM 2048
#define NELEM (T_DIM * B_DIM)

__device__ __forceinline__ float tanh_xla(float x) {
  // Eigen/XLA generic_fast_tanh_float
  const float kClamp = 7.99881172180175781f;
  float xc = fminf(fmaxf(x, -kClamp), kClamp);
  float x2 = xc * xc;
  float p = fmaf(x2, -2.76076847742355e-16f, 2.00018790482477e-13f);
  p = fmaf(x2, p, -8.60467152213735e-11f);
  p = fmaf(x2, p, 5.12229709037114e-08f);
  p = fmaf(x2, p, 1.48572235717979e-05f);
  p = fmaf(x2, p, 6.37261928875436e-04f);
  p = fmaf(x2, p, 4.89352455891786e-03f);
  p = xc * p;
  float q = fmaf(x2, 1.19825839466702e-06f, 1.18534705686654e-04f);
  q = fmaf(x2, q, 2.26843463243900e-03f);
  q = fmaf(x2, q, 4.89352518554385e-03f);
  float r = p / q;
  return (fabsf(x) < 0.0004f) ? x : r;
}

__device__ __forceinline__ float sigmoid_xla(float x) {
  return 0.5f + 0.5f * tanh_xla(0.5f * x);
}

__device__ __forceinline__ int ternary_digit(float v) {
  float soft = 1.5f * tanh_xla(v) + 0.5f * tanh_xla(-3.0f * v);
  return (int)rintf(soft) + 1;
}

__device__ __forceinline__ float blane(float v, int j) {
  return __int_as_float(__builtin_amdgcn_readlane(__float_as_int(v), j));
}

// ---------------- K1: obs encoder -> xcode[T*B] ----------------
__global__ __launch_bounds__(256) void k_obs(
    const float* __restrict__ x,
    const float* __restrict__ w0, const float* __restrict__ b0,
    const float* __restrict__ w1, const float* __restrict__ b1,
    const float* __restrict__ w2, const float* __restrict__ b2,
    unsigned short* __restrict__ xcodes) {
  int e = blockIdx.x * 256 + threadIdx.x;  // grid is exact
  const float* xr = x + (size_t)e * 64;
  float xv[64];
#pragma unroll
  for (int j = 0; j < 64; j += 4) {
    float4 v = *reinterpret_cast<const float4*>(xr + j);
    xv[j] = v.x; xv[j + 1] = v.y; xv[j + 2] = v.z; xv[j + 3] = v.w;
  }
  float h1[28];
#pragma unroll
  for (int k = 0; k < 28; ++k) {
    float acc = 0.0f;
#pragma unroll
    for (int j = 0; j < 64; ++j) acc = fmaf(w0[k * 64 + j], xv[j], acc);
    h1[k] = tanh_xla(acc + b0[k]);
  }
  float h2[28];
#pragma unroll
  for (int k = 0; k < 28; ++k) {
    float acc = 0.0f;
#pragma unroll
    for (int j = 0; j < 28; ++j) acc = fmaf(w1[k * 28 + j], h1[j], acc);
    h2[k] = tanh_xla(acc + b1[k]);
  }
  const int p3[8] = {1, 3, 9, 27, 81, 243, 729, 2187};
  unsigned code = 0;
#pragma unroll
  for (int k = 0; k < 8; ++k) {
    float acc = 0.0f;
#pragma unroll
    for (int j = 0; j < 28; ++j) acc = fmaf(w2[k * 28 + j], h2[j], acc);
    code += (unsigned)(ternary_digit(acc + b2[k]) * p3[k]);
  }
  xcodes[e] = (unsigned short)code;
}

// ---------------- K2: GI table [6561][64] ----------------
__global__ __launch_bounds__(256) void k_gi(
    const float* __restrict__ wih, const float* __restrict__ bih,
    float* __restrict__ gip) {
  int c = blockIdx.x * 256 + threadIdx.x;
  if (c >= 6561) return;
  float q[8];
  unsigned cc = (unsigned)c;
#pragma unroll
  for (int k = 0; k < 8; ++k) { q[k] = (float)((int)(cc % 3u) - 1); cc /= 3u; }
#pragma unroll
  for (int i = 0; i < 16; ++i) {
    float gr = 0.f, gz = 0.f, gn = 0.f;
#pragma unroll
    for (int j = 0; j < 8; ++j) {
      gr = fmaf(wih[i * 8 + j], q[j], gr);
      gz = fmaf(wih[(16 + i) * 8 + j], q[j], gz);
      gn = fmaf(wih[(32 + i) * 8 + j], q[j], gn);
    }
    float4 o;
    o.x = gr + bih[i]; o.y = gz + bih[16 + i]; o.z = gn + bih[32 + i]; o.w = 0.f;
    *reinterpret_cast<float4*>(gip + (size_t)c * 64 + i * 4) = o;
  }
}

// ---------------- K3: GHM [6562][64] + Y [6561][16] ----------------
__global__ __launch_bounds__(256) void k_mtab(
    const float* __restrict__ q2m_w0, const float* __restrict__ q2m_b0,
    const float* __restrict__ q2m_w1, const float* __restrict__ q2m_b1,
    const float* __restrict__ q2m_w2, const float* __restrict__ q2m_b2,
    const float* __restrict__ whh, const float* __restrict__ bhh,
    const float* __restrict__ act_w, const float* __restrict__ act_b,
    float* __restrict__ ghm, float* __restrict__ ytab) {
  int c = blockIdx.x * 256 + threadIdx.x;
  if (c > 6561) return;
  float m[16];
  if (c == 6561) {
#pragma unroll
    for (int i = 0; i < 16; ++i) m[i] = 0.0f;  // h0 = 0
  } else {
    float q[8];
    unsigned cc = (unsigned)c;
#pragma unroll
    for (int k = 0; k < 8; ++k) { q[k] = (float)((int)(cc % 3u) - 1); cc /= 3u; }
    float a[16];
#pragma unroll
    for (int i = 0; i < 16; ++i) {
      float acc = 0.f;
#pragma unroll
      for (int j = 0; j < 8; ++j) acc = fmaf(q2m_w0[i * 8 + j], q[j], acc);
      a[i] = tanh_xla(acc + q2m_b0[i]);
    }
    float d[16];
#pragma unroll
    for (int i = 0; i < 16; ++i) {
      float acc = 0.f;
#pragma unroll
      for (int j = 0; j < 16; ++j) acc = fmaf(q2m_w1[i * 16 + j], a[j], acc);
      d[i] = tanh_xla(acc + q2m_b1[i]);
    }
#pragma unroll
    for (int i = 0; i < 16; ++i) {
      float acc = 0.f;
#pragma unroll
      for (int j = 0; j < 16; ++j) acc = fmaf(q2m_w2[i * 16 + j], d[j], acc);
      m[i] = tanh_xla(acc + q2m_b2[i]);
    }
  }
#pragma unroll
  for (int i = 0; i < 16; ++i) {
    float gr = 0.f, gz = 0.f, gn = 0.f;
#pragma unroll
    for (int j = 0; j < 16; ++j) {
      gr = fmaf(whh[i * 16 + j], m[j], gr);
      gz = fmaf(whh[(16 + i) * 16 + j], m[j], gz);
      gn = fmaf(whh[(32 + i) * 16 + j], m[j], gn);
    }
    float4 o;
    o.x = gr + bhh[i]; o.y = gz + bhh[16 + i]; o.z = gn + bhh[32 + i]; o.w = m[i];
    *reinterpret_cast<float4*>(ghm + (size_t)c * 64 + i * 4) = o;
  }
  if (c < 6561) {
#pragma unroll
    for (int i = 0; i < 16; ++i) {
      float acc = 0.f;
#pragma unroll
      for (int j = 0; j < 16; ++j) acc = fmaf(act_w[i * 16 + j], m[j], acc);
      ytab[(size_t)c * 16 + i] = tanh_xla(acc + act_b[i]);
    }
  }
}

// ---------------- K4: the scan. ONE chain per wave ----------------
__global__ __launch_bounds__(64) void k_scan(
    const unsigned short* __restrict__ xcodes,
    const float* __restrict__ ghm,  // [6562][64]
    const float* __restrict__ gip,  // [6561][64]
    const float* __restrict__ m2q_w0, const float* __restrict__ m2q_b0,
    const float* __restrict__ m2q_w1, const float* __restrict__ m2q_b1,
    const float* __restrict__ m2q_w2, const float* __restrict__ m2q_b2,
    unsigned short* __restrict__ qcodes) {
  const int lane = threadIdx.x & 15;  // all 4 sixteen-groups mirror lanes 0-15
  const int b = blockIdx.x;           // one batch element per wave (grid 2048)

  // per-lane m2q weight rows (lanes 16-63 mirror 0-15)
  float w0r[16], w1r[16], w2r[16];
#pragma unroll
  for (int j = 0; j < 16; j += 4) {
    float4 a = *reinterpret_cast<const float4*>(m2q_w0 + lane * 16 + j);
    w0r[j] = a.x; w0r[j + 1] = a.y; w0r[j + 2] = a.z; w0r[j + 3] = a.w;
    float4 bq = *reinterpret_cast<const float4*>(m2q_w1 + lane * 16 + j);
    w1r[j] = bq.x; w1r[j + 1] = bq.y; w1r[j + 2] = bq.z; w1r[j + 3] = bq.w;
    float4 cq = *reinterpret_cast<const float4*>(m2q_w2 + (lane & 7) * 16 + j);
    w2r[j] = cq.x; w2r[j + 1] = cq.y; w2r[j + 2] = cq.z; w2r[j + 3] = cq.w;
  }
  const float b0l = m2q_b0[lane], b1l = m2q_b1[lane], b2l = m2q_b2[lane & 7];

  const float4* __restrict__ ghm4 = (const float4*)ghm;
  const float4* __restrict__ gip4 = (const float4*)gip;

  int qcode = 6561;  // initial-state row
  unsigned xc = xcodes[b];  // wave-uniform -> scalar load
  float4 i4 = gip4[(int)xc * 16 + lane];

  for (int t = 0; t < T_DIM; ++t) {
    float4 g4 = ghm4[qcode * 16 + lane];  // uniform row + lane offset (saddr)
    // prefetch next step's GI row (independent of the qcode chain)
    int tn = (t + 1 < T_DIM) ? t + 1 : T_DIM - 1;
    unsigned xcn = xcodes[tn * B_DIM + b];  // wave-uniform scalar load
    float4 i4n = gip4[(int)xcn * 16 + lane];

    float r = sigmoid_xla(i4.x + g4.x);
    float z = sigmoid_xla(i4.y + g4.y);
    float n = tanh_xla(fmaf(r, g4.z, i4.z));
    float h = (1.0f - z) * n + z * g4.w;

    // layer 0: broadcast h_j via readlane (VALU, no DS)
    float acc = 0.f;
#pragma unroll
    for (int j = 0; j < 16; ++j) acc = fmaf(w0r[j], blane(h, j), acc);
    float t0 = tanh_xla(acc + b0l);
    // layer 1
    acc = 0.f;
#pragma unroll
    for (int j = 0; j < 16; ++j) acc = fmaf(w1r[j], blane(t0, j), acc);
    float t1 = tanh_xla(acc + b1l);
    // layer 2 (8 rows; lanes mirror by &7)
    acc = 0.f;
#pragma unroll
    for (int j = 0; j < 16; ++j) acc = fmaf(w2r[j], blane(t1, j), acc);
    int d = ternary_digit(acc + b2l);  // 0..2, meaningful on lanes 0..7

    // wave-uniform digit collect: 8 readlanes + scalar mads
    int qc = __builtin_amdgcn_readlane(d, 0);
    qc += __builtin_amdgcn_readlane(d, 1) * 3;
    qc += __builtin_amdgcn_readlane(d, 2) * 9;
    qc += __builtin_amdgcn_readlane(d, 3) * 27;
    qc += __builtin_amdgcn_readlane(d, 4) * 81;
    qc += __builtin_amdgcn_readlane(d, 5) * 243;
    qc += __builtin_amdgcn_readlane(d, 6) * 729;
    qc += __builtin_amdgcn_readlane(d, 7) * 2187;
    qcode = qc;

    if (threadIdx.x == 0) qcodes[t * B_DIM + b] = (unsigned short)qcode;
    i4 = i4n;
  }
}

// ---------------- K5: output gather out[e] = Y[qcode[e]] ----------------
__global__ __launch_bounds__(256) void k_out(
    const unsigned short* __restrict__ qcodes,
    const float* __restrict__ ytab,
    float* __restrict__ out) {
  int i = blockIdx.x * 256 + threadIdx.x;  // over NELEM*4 float4s, grid exact
  int e = i >> 2, sub = i & 3;
  unsigned c = qcodes[e];
  float4 y = *reinterpret_cast<const float4*>(ytab + (size_t)c * 16 + sub * 4);
  reinterpret_cast<float4*>(out)[i] = y;
}

extern "C" void kernel_launch(void* const* d_in, const int* in_sizes, int n_in,
                              void* d_out, int out_size, void* d_ws, size_t ws_size,
                              hipStream_t stream) {
  (void)in_sizes; (void)n_in; (void)out_size; (void)ws_size;
  const float* x       = (const float*)d_in[0];
  const float* obs_w0  = (const float*)d_in[1];
  const float* obs_b0  = (const float*)d_in[2];
  const float* obs_w1  = (const float*)d_in[3];
  const float* obs_b1  = (const float*)d_in[4];
  const float* obs_w2  = (const float*)d_in[5];
  const float* obs_b2  = (const float*)d_in[6];
  const float* gru_wih = (const float*)d_in[7];
  const float* gru_whh = (const float*)d_in[8];
  const float* gru_bih = (const float*)d_in[9];
  const float* gru_bhh = (const float*)d_in[10];
  const float* m2q_w0  = (const float*)d_in[11];
  const float* m2q_b0  = (const float*)d_in[12];
  const float* m2q_w1  = (const float*)d_in[13];
  const float* m2q_b1  = (const float*)d_in[14];
  const float* m2q_w2  = (const float*)d_in[15];
  const float* m2q_b2  = (const float*)d_in[16];
  const float* q2m_w0  = (const float*)d_in[17];
  const float* q2m_b0  = (const float*)d_in[18];
  const float* q2m_w1  = (const float*)d_in[19];
  const float* q2m_b1  = (const float*)d_in[20];
  const float* q2m_w2  = (const float*)d_in[21];
  const float* q2m_b2  = (const float*)d_in[22];
  const float* act_w   = (const float*)d_in[23];
  const float* act_b   = (const float*)d_in[24];

  char* ws = (char*)d_ws;
  unsigned short* xcodes = (unsigned short*)(ws);
  unsigned short* qcodes = (unsigned short*)(ws + (2u << 20));
  float* gip  = (float*)(ws + (4u << 20));
  float* ghm  = (float*)(ws + (6u << 20));
  float* ytab = (float*)(ws + (8u << 20));

  k_gi<<<26, 256, 0, stream>>>(gru_wih, gru_bih, gip);
  k_mtab<<<26, 256, 0, stream>>>(q2m_w0, q2m_b0, q2m_w1, q2m_b1, q2m_w2, q2m_b2,
                                 gru_whh, gru_bhh, act_w, act_b, ghm, ytab);
  k_obs<<<NELEM / 256, 256, 0, stream>>>(x, obs_w0, obs_b0, obs_w1, obs_b1,
                                         obs_w2, obs_b2, xcodes);
  k_scan<<<B_DIM, 64, 0, stream>>>(xcodes, ghm, gip,
                                   m2q_w0, m2q_b0, m2q_w1, m2q_b1,
                                   m2q_w2, m2q_b2, qcodes);
  k_out<<<(NELEM * 4) / 256, 256, 0, stream>>>(qcodes, ytab, (float*)d_out);
}

// Round 4
// 1167.052 us; speedup vs baseline: 1.2166x; 1.2166x over previous
//
#include <hip/hip_runtime.h>

// QBN_GRU_Base on MI355X.
// Ternary bottlenecks (dim 8) make the recurrence finite-state:
//   xq, q in {-1,0,1}^8 -> 6561 codes. Memoize
//     GI[code][64]   = xq@wih.T + bih            (packed [i*4+{r,z,n,pad}])
//     GHM[code][64]  = {m@whh.T + bhh, m}        (packed [i*4+{r,z,n,m}], row 6561 = h0 state)
//     Y[code][16]    = tanh(m@act_w.T + act_b)
// R4: back to 4 chains/wave (512 waves, lane-efficient). ALL cross-lane ops
// via DPP (row_newbcast for broadcasts, row_shr prefix for the digit sum) —
// zero DS-pipe ops, zero readlane hazards in the scan loop.
// Numerics: XLA/Eigen rational tanh, logistic = 0.5+0.5*tanh(0.5x), fma dots —
// all float expressions feeding digits identical to the absmax==0.0 kernels.

#define T_DIM 512
#define B_DIM 2048
#define NELEM (T_DIM * B_DIM)

__device__ __forceinline__ float tanh_xla(float x) {
  // Eigen/XLA generic_fast_tanh_float
  const float kClamp = 7.99881172180175781f;
  float xc = fminf(fmaxf(x, -kClamp), kClamp);
  float x2 = xc * xc;
  float p = fmaf(x2, -2.76076847742355e-16f, 2.00018790482477e-13f);
  p = fmaf(x2, p, -8.60467152213735e-11f);
  p = fmaf(x2, p, 5.12229709037114e-08f);
  p = fmaf(x2, p, 1.48572235717979e-05f);
  p = fmaf(x2, p, 6.37261928875436e-04f);
  p = fmaf(x2, p, 4.89352455891786e-03f);
  p = xc * p;
  float q = fmaf(x2, 1.19825839466702e-06f, 1.18534705686654e-04f);
  q = fmaf(x2, q, 2.26843463243900e-03f);
  q = fmaf(x2, q, 4.89352518554385e-03f);
  float r = p / q;
  return (fabsf(x) < 0.0004f) ? x : r;
}

__device__ __forceinline__ float sigmoid_xla(float x) {
  return 0.5f + 0.5f * tanh_xla(0.5f * x);
}

__device__ __forceinline__ int ternary_digit(float v) {
  float soft = 1.5f * tanh_xla(v) + 0.5f * tanh_xla(-3.0f * v);
  return (int)rintf(soft) + 1;
}

// DPP broadcast of lane J within each 16-lane row (ROW_NEWBCAST, ctrl 0x150+J)
template <int J>
__device__ __forceinline__ float bcastJ(float v) {
  int s = __float_as_int(v);
  return __int_as_float(
      __builtin_amdgcn_update_dpp(s, s, 0x150 + J, 0xF, 0xF, false));
}

// v + (v shifted right by N lanes within the row), OOB reads -> 0
template <int N>
__device__ __forceinline__ float shr_add(float v) {
  return v + __int_as_float(__builtin_amdgcn_update_dpp(
                 0, __float_as_int(v), 0x110 + N, 0xF, 0xF, true));
}

// ---------------- K1: obs encoder -> xcode[T*B] ----------------
__global__ __launch_bounds__(256) void k_obs(
    const float* __restrict__ x,
    const float* __restrict__ w0, const float* __restrict__ b0,
    const float* __restrict__ w1, const float* __restrict__ b1,
    const float* __restrict__ w2, const float* __restrict__ b2,
    unsigned short* __restrict__ xcodes) {
  int e = blockIdx.x * 256 + threadIdx.x;  // grid is exact
  const float* xr = x + (size_t)e * 64;
  float xv[64];
#pragma unroll
  for (int j = 0; j < 64; j += 4) {
    float4 v = *reinterpret_cast<const float4*>(xr + j);
    xv[j] = v.x; xv[j + 1] = v.y; xv[j + 2] = v.z; xv[j + 3] = v.w;
  }
  float h1[28];
#pragma unroll
  for (int k = 0; k < 28; ++k) {
    float acc = 0.0f;
#pragma unroll
    for (int j = 0; j < 64; ++j) acc = fmaf(w0[k * 64 + j], xv[j], acc);
    h1[k] = tanh_xla(acc + b0[k]);
  }
  float h2[28];
#pragma unroll
  for (int k = 0; k < 28; ++k) {
    float acc = 0.0f;
#pragma unroll
    for (int j = 0; j < 28; ++j) acc = fmaf(w1[k * 28 + j], h1[j], acc);
    h2[k] = tanh_xla(acc + b1[k]);
  }
  const int p3[8] = {1, 3, 9, 27, 81, 243, 729, 2187};
  unsigned code = 0;
#pragma unroll
  for (int k = 0; k < 8; ++k) {
    float acc = 0.0f;
#pragma unroll
    for (int j = 0; j < 28; ++j) acc = fmaf(w2[k * 28 + j], h2[j], acc);
    code += (unsigned)(ternary_digit(acc + b2[k]) * p3[k]);
  }
  xcodes[e] = (unsigned short)code;
}

// ---------------- K2: GI table [6561][64] ----------------
__global__ __launch_bounds__(256) void k_gi(
    const float* __restrict__ wih, const float* __restrict__ bih,
    float* __restrict__ gip) {
  int c = blockIdx.x * 256 + threadIdx.x;
  if (c >= 6561) return;
  float q[8];
  unsigned cc = (unsigned)c;
#pragma unroll
  for (int k = 0; k < 8; ++k) { q[k] = (float)((int)(cc % 3u) - 1); cc /= 3u; }
#pragma unroll
  for (int i = 0; i < 16; ++i) {
    float gr = 0.f, gz = 0.f, gn = 0.f;
#pragma unroll
    for (int j = 0; j < 8; ++j) {
      gr = fmaf(wih[i * 8 + j], q[j], gr);
      gz = fmaf(wih[(16 + i) * 8 + j], q[j], gz);
      gn = fmaf(wih[(32 + i) * 8 + j], q[j], gn);
    }
    float4 o;
    o.x = gr + bih[i]; o.y = gz + bih[16 + i]; o.z = gn + bih[32 + i]; o.w = 0.f;
    *reinterpret_cast<float4*>(gip + (size_t)c * 64 + i * 4) = o;
  }
}

// ---------------- K3: GHM [6562][64] + Y [6561][16] ----------------
__global__ __launch_bounds__(256) void k_mtab(
    const float* __restrict__ q2m_w0, const float* __restrict__ q2m_b0,
    const float* __restrict__ q2m_w1, const float* __restrict__ q2m_b1,
    const float* __restrict__ q2m_w2, const float* __restrict__ q2m_b2,
    const float* __restrict__ whh, const float* __restrict__ bhh,
    const float* __restrict__ act_w, const float* __restrict__ act_b,
    float* __restrict__ ghm, float* __restrict__ ytab) {
  int c = blockIdx.x * 256 + threadIdx.x;
  if (c > 6561) return;
  float m[16];
  if (c == 6561) {
#pragma unroll
    for (int i = 0; i < 16; ++i) m[i] = 0.0f;  // h0 = 0
  } else {
    float q[8];
    unsigned cc = (unsigned)c;
#pragma unroll
    for (int k = 0; k < 8; ++k) { q[k] = (float)((int)(cc % 3u) - 1); cc /= 3u; }
    float a[16];
#pragma unroll
    for (int i = 0; i < 16; ++i) {
      float acc = 0.f;
#pragma unroll
      for (int j = 0; j < 8; ++j) acc = fmaf(q2m_w0[i * 8 + j], q[j], acc);
      a[i] = tanh_xla(acc + q2m_b0[i]);
    }
    float d[16];
#pragma unroll
    for (int i = 0; i < 16; ++i) {
      float acc = 0.f;
#pragma unroll
      for (int j = 0; j < 16; ++j) acc = fmaf(q2m_w1[i * 16 + j], a[j], acc);
      d[i] = tanh_xla(acc + q2m_b1[i]);
    }
#pragma unroll
    for (int i = 0; i < 16; ++i) {
      float acc = 0.f;
#pragma unroll
      for (int j = 0; j < 16; ++j) acc = fmaf(q2m_w2[i * 16 + j], d[j], acc);
      m[i] = tanh_xla(acc + q2m_b2[i]);
    }
  }
#pragma unroll
  for (int i = 0; i < 16; ++i) {
    float gr = 0.f, gz = 0.f, gn = 0.f;
#pragma unroll
    for (int j = 0; j < 16; ++j) {
      gr = fmaf(whh[i * 16 + j], m[j], gr);
      gz = fmaf(whh[(16 + i) * 16 + j], m[j], gz);
      gn = fmaf(whh[(32 + i) * 16 + j], m[j], gn);
    }
    float4 o;
    o.x = gr + bhh[i]; o.y = gz + bhh[16 + i]; o.z = gn + bhh[32 + i]; o.w = m[i];
    *reinterpret_cast<float4*>(ghm + (size_t)c * 64 + i * 4) = o;
  }
  if (c < 6561) {
#pragma unroll
    for (int i = 0; i < 16; ++i) {
      float acc = 0.f;
#pragma unroll
      for (int j = 0; j < 16; ++j) acc = fmaf(act_w[i * 16 + j], m[j], acc);
      ytab[(size_t)c * 16 + i] = tanh_xla(acc + act_b[i]);
    }
  }
}

// ---------------- K4: the scan. 4 chains/wave, DPP-only cross-lane ----------
#define DOT16(ACC, W, V)                    \
  ACC = fmaf(W[0], bcastJ<0>(V), ACC);      \
  ACC = fmaf(W[1], bcastJ<1>(V), ACC);      \
  ACC = fmaf(W[2], bcastJ<2>(V), ACC);      \
  ACC = fmaf(W[3], bcastJ<3>(V), ACC);      \
  ACC = fmaf(W[4], bcastJ<4>(V), ACC);      \
  ACC = fmaf(W[5], bcastJ<5>(V), ACC);      \
  ACC = fmaf(W[6], bcastJ<6>(V), ACC);      \
  ACC = fmaf(W[7], bcastJ<7>(V), ACC);      \
  ACC = fmaf(W[8], bcastJ<8>(V), ACC);      \
  ACC = fmaf(W[9], bcastJ<9>(V), ACC);      \
  ACC = fmaf(W[10], bcastJ<10>(V), ACC);    \
  ACC = fmaf(W[11], bcastJ<11>(V), ACC);    \
  ACC = fmaf(W[12], bcastJ<12>(V), ACC);    \
  ACC = fmaf(W[13], bcastJ<13>(V), ACC);    \
  ACC = fmaf(W[14], bcastJ<14>(V), ACC);    \
  ACC = fmaf(W[15], bcastJ<15>(V), ACC);

__global__ __launch_bounds__(64) void k_scan(
    const unsigned short* __restrict__ xcodes,
    const float* __restrict__ ghm,  // [6562][64]
    const float* __restrict__ gip,  // [6561][64]
    const float* __restrict__ m2q_w0, const float* __restrict__ m2q_b0,
    const float* __restrict__ m2q_w1, const float* __restrict__ m2q_b1,
    const float* __restrict__ m2q_w2, const float* __restrict__ m2q_b2,
    unsigned short* __restrict__ qcodes) {
  int lane = threadIdx.x & 15;
  int b = (blockIdx.x * 64 + threadIdx.x) >> 4;  // 0..2047
  int lane16 = lane * 16;                        // byte offset of lane's float4

  // per-lane m2q weight rows
  float w0r[16], w1r[16], w2r[16];
#pragma unroll
  for (int j = 0; j < 16; j += 4) {
    float4 a = *reinterpret_cast<const float4*>(m2q_w0 + lane * 16 + j);
    w0r[j] = a.x; w0r[j + 1] = a.y; w0r[j + 2] = a.z; w0r[j + 3] = a.w;
    float4 bq = *reinterpret_cast<const float4*>(m2q_w1 + lane * 16 + j);
    w1r[j] = bq.x; w1r[j + 1] = bq.y; w1r[j + 2] = bq.z; w1r[j + 3] = bq.w;
    float4 cq = *reinterpret_cast<const float4*>(m2q_w2 + (lane & 7) * 16 + j);
    w2r[j] = cq.x; w2r[j + 1] = cq.y; w2r[j + 2] = cq.z; w2r[j + 3] = cq.w;
  }
  float b0l = m2q_b0[lane], b1l = m2q_b1[lane], b2l = m2q_b2[lane & 7];
  // digit weight: 3^(lane)*256 for lanes 0..7, else 0 (exact in fp32)
  int p3i = 1;
  for (int k = 0; k < (lane & 7); ++k) p3i *= 3;
  float w3f = (lane < 8) ? (float)(p3i * 256) : 0.0f;
  const int kOffBias = 3280 * 256;  // sum of 3^k*256, k=0..7

  const char* ghmB = (const char*)ghm;
  const char* gipB = (const char*)gip;

  int qoff = 6561 * 256;  // byte offset of initial-state row
  unsigned xc = xcodes[b];
  float4 i4 = *reinterpret_cast<const float4*>(gipB + (unsigned)(((int)xc << 8) + lane16));

  for (int t = 0; t < T_DIM; ++t) {
    float4 g4 = *reinterpret_cast<const float4*>(ghmB + (unsigned)(qoff + lane16));
    // prefetch next step's GI row (independent of the qcode chain)
    int tn = (t + 1 < T_DIM) ? t + 1 : T_DIM - 1;
    unsigned xcn = xcodes[tn * B_DIM + b];
    float4 i4n = *reinterpret_cast<const float4*>(gipB + (unsigned)(((int)xcn << 8) + lane16));

    float r = sigmoid_xla(i4.x + g4.x);
    float z = sigmoid_xla(i4.y + g4.y);
    float n = tanh_xla(fmaf(r, g4.z, i4.z));
    float h = (1.0f - z) * n + z * g4.w;

    float acc = 0.f;
    DOT16(acc, w0r, h)
    float t0 = tanh_xla(acc + b0l);
    acc = 0.f;
    DOT16(acc, w1r, t0)
    float t1 = tanh_xla(acc + b1l);
    acc = 0.f;
    DOT16(acc, w2r, t1)
    // ternary digit as float, pre-scaled by 3^k*256 (exact integers in fp32)
    float s = acc + b2l;
    float soft = 1.5f * tanh_xla(s) + 0.5f * tanh_xla(-3.0f * s);
    float valf = rintf(soft) * w3f;  // lanes 8..15 -> 0
    // DPP prefix-sum within the row: lane 7 = sum of lanes 0..7
    float ps = shr_add<1>(valf);
    ps = shr_add<2>(ps);
    ps = shr_add<4>(ps);
    float tot = bcastJ<7>(ps);       // row-uniform scaled qcode
    qoff = (int)tot + kOffBias;       // byte offset = qcode*256

    if (lane == 0) qcodes[t * B_DIM + b] = (unsigned short)((unsigned)qoff >> 8);
    i4 = i4n;
  }
}

// ---------------- K5: output gather out[e] = Y[qcode[e]] ----------------
__global__ __launch_bounds__(256) void k_out(
    const unsigned short* __restrict__ qcodes,
    const float* __restrict__ ytab,
    float* __restrict__ out) {
  int i = blockIdx.x * 256 + threadIdx.x;  // over NELEM*4 float4s, grid exact
  int e = i >> 2, sub = i & 3;
  unsigned c = qcodes[e];
  float4 y = *reinterpret_cast<const float4*>(ytab + (size_t)c * 16 + sub * 4);
  reinterpret_cast<float4*>(out)[i] = y;
}

extern "C" void kernel_launch(void* const* d_in, const int* in_sizes, int n_in,
                              void* d_out, int out_size, void* d_ws, size_t ws_size,
                              hipStream_t stream) {
  (void)in_sizes; (void)n_in; (void)out_size; (void)ws_size;
  const float* x       = (const float*)d_in[0];
  const float* obs_w0  = (const float*)d_in[1];
  const float* obs_b0  = (const float*)d_in[2];
  const float* obs_w1  = (const float*)d_in[3];
  const float* obs_b1  = (const float*)d_in[4];
  const float* obs_w2  = (const float*)d_in[5];
  const float* obs_b2  = (const float*)d_in[6];
  const float* gru_wih = (const float*)d_in[7];
  const float* gru_whh = (const float*)d_in[8];
  const float* gru_bih = (const float*)d_in[9];
  const float* gru_bhh = (const float*)d_in[10];
  const float* m2q_w0  = (const float*)d_in[11];
  const float* m2q_b0  = (const float*)d_in[12];
  const float* m2q_w1  = (const float*)d_in[13];
  const float* m2q_b1  = (const float*)d_in[14];
  const float* m2q_w2  = (const float*)d_in[15];
  const float* m2q_b2  = (const float*)d_in[16];
  const float* q2m_w0  = (const float*)d_in[17];
  const float* q2m_b0  = (const float*)d_in[18];
  const float* q2m_w1  = (const float*)d_in[19];
  const float* q2m_b1  = (const float*)d_in[20];
  const float* q2m_w2  = (const float*)d_in[21];
  const float* q2m_b2  = (const float*)d_in[22];
  const float* act_w   = (const float*)d_in[23];
  const float* act_b   = (const float*)d_in[24];

  char* ws = (char*)d_ws;
  unsigned short* xcodes = (unsigned short*)(ws);
  unsigned short* qcodes = (unsigned short*)(ws + (2u << 20));
  float* gip  = (float*)(ws + (4u << 20));
  float* ghm  = (float*)(ws + (6u << 20));
  float* ytab = (float*)(ws + (8u << 20));

  k_gi<<<26, 256, 0, stream>>>(gru_wih, gru_bih, gip);
  k_mtab<<<26, 256, 0, stream>>>(q2m_w0, q2m_b0, q2m_w1, q2m_b1, q2m_w2, q2m_b2,
                                 gru_whh, gru_bhh, act_w, act_b, ghm, ytab);
  k_obs<<<NELEM / 256, 256, 0, stream>>>(x, obs_w0, obs_b0, obs_w1, obs_b1,
                                         obs_w2, obs_b2, xcodes);
  k_scan<<<(B_DIM * 16) / 64, 64, 0, stream>>>(xcodes, ghm, gip,
                                               m2q_w0, m2q_b0, m2q_w1, m2q_b1,
                                               m2q_w2, m2q_b2, qcodes);
  k_out<<<(NELEM * 4) / 256, 256, 0, stream>>>(qcodes, ytab, (float*)d_out);
}